// Round 8
// baseline (401.292 us; speedup 1.0000x reference)
//
#include <hip/hip_runtime.h>
#include <hip/hip_bf16.h>
#include <math.h>

// B=64, NS=16, NF=4096, D=128, H=256. All tensors fp32; bf16 packing is used
// internally (k/q) for the attention dot-products only; v stays fp32.
#define B_  64
#define NS_ 16
#define NF_ 4096
#define D_  128
#define H_  256

// ws layout (bytes):
//   [0      , 262144): q as bf16 pairs [B][NS][D]
//   [262144 , 786432): attended accumulator fp32 [B][NS][D]
//   [786432 , 790528): denom fp32 [B][NS]

typedef __attribute__((ext_vector_type(8))) short bf16x8;
typedef __attribute__((ext_vector_type(4))) float f32x4;

__device__ __forceinline__ bf16x8 as_bf16x8(uint4 u) {
    union { uint4 u; bf16x8 h; } c; c.u = u; return c.h;
}

// pack two fp32 -> bf16 pair with round-to-nearest-even
__device__ __forceinline__ unsigned int pk_bf16(float a, float b) {
    unsigned int ua = __float_as_uint(a), ub = __float_as_uint(b);
    ua = (ua + 0x7FFFu + ((ua >> 16) & 1u)) >> 16;
    ub = (ub + 0x7FFFu + ((ub >> 16) & 1u)) >> 16;
    return ua | (ub << 16);
}

__device__ __forceinline__ float dot4(float4 a, float4 b) {
    return a.x * b.x + a.y * b.y + a.z * b.z + a.w * b.w;
}

// ---------------- Kernel 1: LN(slots) @ Wq^T -> q (bf16 pairs) -------------
// v2: grid 256 = (batch, n-quartet); 128 threads. 4x the CU coverage of the
// old 64-block version (which left 192 CUs idle and ran only 2 waves each).
// Wq is 64 KB and L2-resident; re-reading it per block is latency-cheap.
__global__ __launch_bounds__(128) void k_q(
    const float* __restrict__ slots, const float* __restrict__ Wq,
    const float* __restrict__ lng, const float* __restrict__ lnb,
    unsigned int* __restrict__ q_out, float* __restrict__ acc, float* __restrict__ den) {
    const int bid = blockIdx.x;
    const int b = bid >> 2, q4 = bid & 3;   // 4 n-rows per block
    const int t = threadIdx.x;              // 0..127 (= e and d index)
    const int w = t >> 6, l = t & 63;
    __shared__ float norm_s[4][128];
    __shared__ float st_s[4][2][2];
    __shared__ float q_s[4][128];

    // load own 4 slot rows (coalesced per row)
    float sl[4];
#pragma unroll
    for (int r = 0; r < 4; ++r)
        sl[r] = slots[(size_t)b * 2048 + (q4 * 4 + r) * 128 + t];

    // per-row stats: wave-local shfl reduce, cross-wave combine via LDS
#pragma unroll
    for (int r = 0; r < 4; ++r) {
        float s1 = sl[r], s2 = sl[r] * sl[r];
#pragma unroll
        for (int m = 1; m < 64; m <<= 1) { s1 += __shfl_xor(s1, m); s2 += __shfl_xor(s2, m); }
        if (l == 0) { st_s[r][w][0] = s1; st_s[r][w][1] = s2; }
    }
    __syncthreads();

    float gl = lng[t], bl = lnb[t];
#pragma unroll
    for (int r = 0; r < 4; ++r) {
        float s1 = st_s[r][0][0] + st_s[r][1][0];
        float s2 = st_s[r][0][1] + st_s[r][1][1];
        float mu = s1 * (1.0f / 128.0f);
        float var = s2 * (1.0f / 128.0f) - mu * mu;
        float rs = rsqrtf(var + 1e-5f);
        norm_s[r][t] = (sl[r] - mu) * rs * gl + bl;
    }
    __syncthreads();

    // q[r][e=t] = dot(norm[r], Wq[e]); Wq row loaded once, reused 4x
    const float4* wq = (const float4*)(Wq + (size_t)t * 128);
    float qn[4] = {0.f, 0.f, 0.f, 0.f};
#pragma unroll 4
    for (int j = 0; j < 32; ++j) {
        float4 w4 = wq[j];
#pragma unroll
        for (int r = 0; r < 4; ++r) qn[r] += dot4(w4, *(const float4*)&norm_s[r][4 * j]);
    }
#pragma unroll
    for (int r = 0; r < 4; ++r) q_s[r][t] = qn[r];

    // zero own acc rows + den entries
#pragma unroll
    for (int r = 0; r < 4; ++r)
        acc[(size_t)b * 2048 + (q4 * 4 + r) * 128 + t] = 0.f;
    if (t < 4) den[b * 16 + q4 * 4 + t] = 0.f;
    __syncthreads();

    // pack own 4 q rows to bf16 pairs: 256 uints over 128 threads
    unsigned int* qo = q_out + (size_t)b * 1024 + q4 * 256;
#pragma unroll
    for (int i = 0; i < 2; ++i) {
        int u = i * 128 + t;
        int n = u >> 6, e2 = u & 63;
        qo[n * 64 + e2] = pk_bf16(q_s[n][2 * e2], q_s[n][2 * e2 + 1]);
    }
}

// ---------------- Kernel 2: fused attention (r6 structure, best=111us) -----
// grid (32 chunks, 64 batches) x 256 threads; block tile = 128 rows = 2
// sub-tiles of 64. MFMA logits (S^T = mfma(q,k)), split-m PV with 2-oct
// rolling v prefetch, k->v VMEM issue order. Epilogue reduce padded to
// stride 17 (r6's stride-16 was a 32-way bank conflict, 852K/dispatch).
__global__ __launch_bounds__(256) void k_attn(
    const float* __restrict__ kg_, const float* __restrict__ vg_,
    const unsigned int* __restrict__ q_u, float* __restrict__ acc_g, float* __restrict__ denom_g) {
    const int t = threadIdx.x;
    const int w = t >> 6, l = t & 63;
    const int b = blockIdx.y;
    const int lm = l & 15;   // A-row n (q frag) / B-col m (k frag)
    const int g  = l >> 4;   // 8-wide d-chunk within a 32-d K-step
    const int dcol = t & 127;
    const int nh = t >> 7;   // m-half owned in PV

    __shared__ unsigned int lds_u[5632];
    unsigned int* k_s = lds_u;                    // [64 rows][68 dw] bf16 pairs
    float*        p_s = (float*)(lds_u + 4352);   // [64 rows][20] fp32

    // q A-fragments: lane holds q[b][n=lm][32*kk+8*g .. +8]
    uint4 qA[4];
    {
        const uint4* qb = (const uint4*)q_u + ((b * 16 + lm) * 16);
#pragma unroll
        for (int kk = 0; kk < 4; ++kk) qA[kk] = qb[kk * 4 + g];
    }

    float acc[16];
#pragma unroll
    for (int i = 0; i < 16; ++i) acc[i] = 0.f;
    float dn[4] = {0.f, 0.f, 0.f, 0.f};

    const size_t mbase = (size_t)b * NF_ + blockIdx.x * 128;
    const float4* kg4 = (const float4*)kg_ + (mbase + w * 16) * 32;  // own 16 rows
    const float*  vgp = vg_ + mbase * 128 + dcol;

    for (int sub = 0; sub < 2; ++sub) {
        // v rows for this thread's m-half within the sub-tile
        const float* vt = vgp + (size_t)(sub * 64 + nh * 32) * 128;

        // ---- 1. k loads first (vmcnt FIFO: k-pack wait won't drain v)
        const float4* kp = kg4 + sub * 64 * 32;
        float4 ka[4], kb4[4];
#pragma unroll
        for (int i = 0; i < 4; ++i) ka[i] = kp[i * 64 + l];
#pragma unroll
        for (int i = 0; i < 4; ++i) kb4[i] = kp[(4 + i) * 64 + l];

        // ---- 2. v prefetch octs 0,1
        float vva[8], vvb[8];
#pragma unroll
        for (int i = 0; i < 8; ++i) vva[i] = vt[i * 128];
#pragma unroll
        for (int i = 0; i < 8; ++i) vvb[i] = vt[(8 + i) * 128];

        // ---- pack + ds_write k (waits k only; v stays in flight)
#pragma unroll
        for (int i = 0; i < 4; ++i) {
            int r = w * 16 + 2 * i + (l >> 5);
            *(uint2*)&k_s[r * 68 + 2 * (l & 31)] =
                make_uint2(pk_bf16(ka[i].x, ka[i].y), pk_bf16(ka[i].z, ka[i].w));
        }
#pragma unroll
        for (int i = 0; i < 4; ++i) {
            int r = w * 16 + 2 * (4 + i) + (l >> 5);
            *(uint2*)&k_s[r * 68 + 2 * (l & 31)] =
                make_uint2(pk_bf16(kb4[i].x, kb4[i].y), pk_bf16(kb4[i].z, kb4[i].w));
        }

        // ---- logits via MFMA: S^T tile [16n x 16m] for this wave's rows
        f32x4 sacc = {0.f, 0.f, 0.f, 0.f};
#pragma unroll
        for (int kk = 0; kk < 4; ++kk) {
            uint4 kf = *(const uint4*)&k_s[(w * 16 + lm) * 68 + kk * 16 + g * 4];
            sacc = __builtin_amdgcn_mfma_f32_16x16x32_bf16(
                as_bf16x8(qA[kk]), as_bf16x8(kf), sacc, 0, 0, 0);
        }
        // softmax over n (lane holds n = 4g+r at m-col lm); |logits| small,
        // no max-subtraction needed (proven rounds 0-7).
        const float scale = 0.08838834764831845f;  // D^-0.5
        float e0 = __expf(sacc[0] * scale);
        float e1 = __expf(sacc[1] * scale);
        float e2 = __expf(sacc[2] * scale);
        float e3 = __expf(sacc[3] * scale);
        float se = (e0 + e1) + (e2 + e3);
        se += __shfl_xor(se, 16);
        se += __shfl_xor(se, 32);
        float rse = __builtin_amdgcn_rcpf(se);
        float4 pv4 = make_float4(e0 * rse, e1 * rse, e2 * rse, e3 * rse);
        dn[0] += pv4.x; dn[1] += pv4.y; dn[2] += pv4.z; dn[3] += pv4.w;
        *(float4*)&p_s[(w * 16 + lm) * 20 + g * 4] = pv4;
        __syncthreads();   // p rows from all 4 waves visible

        // ---- 3. PV over own 32 m-rows, all 16 n; 2-oct rolling prefetch.
#define PV_CONSUME(VREG, BASE)                                              \
        {                                                                   \
            _Pragma("unroll")                                               \
            for (int i = 0; i < 8; ++i) {                                   \
                int m = nh * 32 + (BASE) + i;                               \
                float vvi = VREG[i];                                        \
                float4 pa = *(const float4*)&p_s[m * 20 + 0];               \
                float4 pb = *(const float4*)&p_s[m * 20 + 4];               \
                float4 pc = *(const float4*)&p_s[m * 20 + 8];               \
                float4 pd = *(const float4*)&p_s[m * 20 + 12];              \
                acc[0]  = fmaf(pa.x, vvi, acc[0]);                          \
                acc[1]  = fmaf(pa.y, vvi, acc[1]);                          \
                acc[2]  = fmaf(pa.z, vvi, acc[2]);                          \
                acc[3]  = fmaf(pa.w, vvi, acc[3]);                          \
                acc[4]  = fmaf(pb.x, vvi, acc[4]);                          \
                acc[5]  = fmaf(pb.y, vvi, acc[5]);                          \
                acc[6]  = fmaf(pb.z, vvi, acc[6]);                          \
                acc[7]  = fmaf(pb.w, vvi, acc[7]);                          \
                acc[8]  = fmaf(pc.x, vvi, acc[8]);                          \
                acc[9]  = fmaf(pc.y, vvi, acc[9]);                          \
                acc[10] = fmaf(pc.z, vvi, acc[10]);                         \
                acc[11] = fmaf(pc.w, vvi, acc[11]);                         \
                acc[12] = fmaf(pd.x, vvi, acc[12]);                         \
                acc[13] = fmaf(pd.y, vvi, acc[13]);                         \
                acc[14] = fmaf(pd.z, vvi, acc[14]);                         \
                acc[15] = fmaf(pd.w, vvi, acc[15]);                         \
            }                                                               \
        }
        PV_CONSUME(vva, 0)
#pragma unroll
        for (int i = 0; i < 8; ++i) vva[i] = vt[(16 + i) * 128];
        PV_CONSUME(vvb, 8)
#pragma unroll
        for (int i = 0; i < 8; ++i) vvb[i] = vt[(24 + i) * 128];
        PV_CONSUME(vva, 16)
        PV_CONSUME(vvb, 24)
#undef PV_CONSUME
        __syncthreads();   // protect k_s/p_s before restage
    }

    // ---- epilogue ----
    // denom: reduce dn over m (lanes&15) then one atomic per (wave, n)
#pragma unroll
    for (int m = 1; m <= 8; m <<= 1) {
#pragma unroll
        for (int r = 0; r < 4; ++r) dn[r] += __shfl_xor(dn[r], m);
    }
    if (lm == 0) {
#pragma unroll
        for (int r = 0; r < 4; ++r)
            atomicAdd(denom_g + b * 16 + g * 4 + r, dn[r]);
    }
    // cross-nh reduce via LDS; stride 17 (coprime 32) = conflict-free
    float* red = (float*)lds_u;   // [128 dcol][17]
    if (nh == 1) {
#pragma unroll
        for (int n = 0; n < 16; ++n) red[dcol * 17 + n] = acc[n];
    }
    __syncthreads();
    if (nh == 0) {
        float* base = acc_g + (size_t)b * 2048 + dcol;
#pragma unroll
        for (int n = 0; n < 16; ++n)
            atomicAdd(base + n * 128, acc[n] + red[dcol * 17 + n]);
    }
}

// ---------------- Kernel 3: GRU + LN + MLP + residual ----------------------
// v2: grid 1024 = one (b,n) row per block, 256 threads -> 4 blocks/CU,
// 16 waves/CU (old: 256 blocks, exactly 1 block/CU, 4 waves -> latency-bound
// serial weight-dot chains). Weights (654 KB) are L2-resident; the 4x
// re-read costs ~19us of aggregate L2 traffic but buys 4x latency hiding.
__global__ __launch_bounds__(256) void k_final(
    const float* __restrict__ acc_g, const float* __restrict__ denom_g,
    const float* __restrict__ slots,
    const float* __restrict__ W_ih, const float* __restrict__ W_hh,
    const float* __restrict__ b_ih, const float* __restrict__ b_n,
    const float* __restrict__ ffg, const float* __restrict__ ffb,
    const float* __restrict__ W0, const float* __restrict__ b0,
    const float* __restrict__ W1, const float* __restrict__ b1,
    float* __restrict__ out) {
    const int bn = blockIdx.x;   // 0..1023
    const int t = threadIdx.x;   // 0..255
    __shared__ float att_s[128], slot_s[128];
    __shared__ float gates_s[4][128];   // rs, is, in, hn
    __shared__ float gru_s[128], gn_s[128];
    __shared__ float h_s[256];
    __shared__ float stat_s[2];
    __shared__ float red2[128];

    // load att/slot (denom broadcast-loaded; same address across lanes)
    if (t < 128) {
        float den = denom_g[bn] + 1e-8f;
        att_s[t] = acc_g[(size_t)bn * 128 + t] / den;
    } else {
        slot_s[t - 128] = slots[(size_t)bn * 128 + (t - 128)];
    }
    __syncthreads();

    // gates rows 0..383: t<256 one row, t<128 a second (rows 256..383)
    for (int g = t; g < 384; g += 256) {
        const float4* wi = (const float4*)(W_ih + (size_t)g * 128);
        const float4* wh = (const float4*)(W_hh + (size_t)g * 128);
        float si = 0.f, sh = 0.f;
#pragma unroll 4
        for (int j = 0; j < 32; ++j) {
            si += dot4(wi[j], *(const float4*)&att_s[4 * j]);
            sh += dot4(wh[j], *(const float4*)&slot_s[4 * j]);
        }
        float bih = b_ih[g];
        if (g < 128)      gates_s[0][g] = si + sh + bih;
        else if (g < 256) gates_s[1][g - 128] = si + sh + bih;
        else { gates_s[2][g - 256] = si + bih; gates_s[3][g - 256] = sh; }
    }
    __syncthreads();

    // GRU: t<128 computes its d
    if (t < 128) {
        float rr = 1.f / (1.f + __expf(-gates_s[0][t]));
        float ii = 1.f / (1.f + __expf(-gates_s[1][t]));
        float nv = tanhf(gates_s[2][t] + rr * (gates_s[3][t] + b_n[t]));
        gru_s[t] = nv + ii * (slot_s[t] - nv);
    }
    __syncthreads();

    // LN stats over 128 d by wave 0
    if (t < 64) {
        float a = gru_s[t], c = gru_s[t + 64];
        float s1 = a + c, s2 = a * a + c * c;
#pragma unroll
        for (int m = 1; m < 64; m <<= 1) { s1 += __shfl_xor(s1, m); s2 += __shfl_xor(s2, m); }
        if (t == 0) {
            float mu = s1 * (1.0f / 128.0f);
            float var = s2 * (1.0f / 128.0f) - mu * mu;
            stat_s[0] = mu;
            stat_s[1] = rsqrtf(var + 1e-5f);
        }
    }
    __syncthreads();
    if (t < 128)
        gn_s[t] = (gru_s[t] - stat_s[0]) * stat_s[1] * ffg[t] + ffb[t];
    __syncthreads();

    // MLP0: t = h-row 0..255
    {
        const float4* w0 = (const float4*)(W0 + (size_t)t * 128);
        float s = 0.f;
#pragma unroll 4
        for (int j = 0; j < 32; ++j) s += dot4(w0[j], *(const float4*)&gn_s[4 * j]);
        h_s[t] = fmaxf(s + b0[t], 0.f);
    }
    __syncthreads();

    // MLP1 split-K: thread (d = t&127, half = t>>7) does a 128-h half-dot
    {
        int d = t & 127, half = t >> 7;
        const float4* w1 = (const float4*)(W1 + (size_t)d * 256 + half * 128);
        float s = 0.f;
#pragma unroll 4
        for (int j = 0; j < 32; ++j) s += dot4(w1[j], *(const float4*)&h_s[half * 128 + 4 * j]);
        if (half == 1) red2[d] = s;
        __syncthreads();
        if (half == 0)
            out[(size_t)bn * 128 + d] = gru_s[d] + s + red2[d] + b1[d] - slot_s[d];
    }
}

extern "C" void kernel_launch(void* const* d_in, const int* in_sizes, int n_in,
                              void* d_out, int out_size, void* d_ws, size_t ws_size,
                              hipStream_t stream) {
    const float* slots = (const float*)d_in[1];
    const float* k     = (const float*)d_in[2];
    const float* v     = (const float*)d_in[3];
    const float* Wq    = (const float*)d_in[4];
    const float* lng   = (const float*)d_in[5];
    const float* lnb   = (const float*)d_in[6];
    const float* W_ih  = (const float*)d_in[7];
    const float* W_hh  = (const float*)d_in[8];
    const float* b_ih  = (const float*)d_in[9];
    const float* b_n   = (const float*)d_in[10];
    const float* ffg   = (const float*)d_in[11];
    const float* ffb   = (const float*)d_in[12];
    const float* W0    = (const float*)d_in[13];
    const float* b0    = (const float*)d_in[14];
    const float* W1    = (const float*)d_in[15];
    const float* b1    = (const float*)d_in[16];

    char* ws = (char*)d_ws;
    unsigned int* q_u = (unsigned int*)ws;
    float* acc = (float*)(ws + 262144);
    float* den = (float*)(ws + 786432);

    k_q<<<dim3(256), dim3(128), 0, stream>>>(slots, Wq, lng, lnb, q_u, acc, den);
    k_attn<<<dim3(32, B_), dim3(256), 0, stream>>>(k, v, q_u, acc, den);
    k_final<<<dim3(1024), dim3(256), 0, stream>>>(acc, den, slots, W_ih, W_hh,
                                                  b_ih, b_n, ffg, ffb, W0, b0, W1, b1,
                                                  (float*)d_out);
}

// Round 9
// 368.575 us; speedup vs baseline: 1.0888x; 1.0888x over previous
//
#include <hip/hip_runtime.h>
#include <hip/hip_bf16.h>
#include <math.h>

// B=64, NS=16, NF=4096, D=128, H=256. All tensors fp32; bf16 packing is used
// internally (k/q) for the attention dot-products only; v stays fp32.
#define B_  64
#define NS_ 16
#define NF_ 4096
#define D_  128
#define H_  256

// ws layout (bytes):
//   [0      , 262144): q as bf16 pairs [B][NS][D]
//   [262144 , 786432): attended accumulator fp32 [B][NS][D]   (atomic fallback)
//   [786432 , 790528): denom fp32 [B][NS]
//   [1048576, 9437184): partial tiles fp32 [B][16 chunk][NS][D]  (if ws fits)

typedef __attribute__((ext_vector_type(8))) short bf16x8;
typedef __attribute__((ext_vector_type(4))) float f32x4;

__device__ __forceinline__ bf16x8 as_bf16x8(uint4 u) {
    union { uint4 u; bf16x8 h; } c; c.u = u; return c.h;
}

// pack two fp32 -> bf16 pair with round-to-nearest-even
__device__ __forceinline__ unsigned int pk_bf16(float a, float b) {
    unsigned int ua = __float_as_uint(a), ub = __float_as_uint(b);
    ua = (ua + 0x7FFFu + ((ua >> 16) & 1u)) >> 16;
    ub = (ub + 0x7FFFu + ((ub >> 16) & 1u)) >> 16;
    return ua | (ub << 16);
}

__device__ __forceinline__ float dot4(float4 a, float4 b) {
    return a.x * b.x + a.y * b.y + a.z * b.z + a.w * b.w;
}

// ---------------- Kernel 1: per-batch LN(slots) @ Wq^T -> q (bf16 pairs) ----
// (r6-original: part of the 375us best config; r8's 256-block variant
// regressed total, reverted.)
__global__ __launch_bounds__(128) void k_q(
    const float* __restrict__ slots, const float* __restrict__ Wq,
    const float* __restrict__ lng, const float* __restrict__ lnb,
    unsigned int* __restrict__ q_out, float* __restrict__ acc, float* __restrict__ den) {
    const int b = blockIdx.x;
    const int t = threadIdx.x;  // 0..127
    __shared__ float sl_s[16][128];
    __shared__ float norm_s[16][128];
    __shared__ float st_s[16][8][2];
    __shared__ float mu_s[16], rs_s[16];
    __shared__ float q_s[16][128];

    const float4* sp = (const float4*)(slots + (size_t)b * 2048);
#pragma unroll
    for (int i = 0; i < 4; ++i) {
        int f = i * 128 + t;
        *(float4*)&sl_s[f >> 5][(f & 31) * 4] = sp[f];
    }
    __syncthreads();

    {
        int n = t >> 3, j = t & 7;
        float s1 = 0.f, s2 = 0.f;
#pragma unroll
        for (int d2 = 0; d2 < 16; ++d2) {
            float x = sl_s[n][j * 16 + d2];
            s1 += x; s2 += x * x;
        }
        st_s[n][j][0] = s1; st_s[n][j][1] = s2;
    }
    __syncthreads();
    if (t < 16) {
        float s1 = 0.f, s2 = 0.f;
#pragma unroll
        for (int j = 0; j < 8; ++j) { s1 += st_s[t][j][0]; s2 += st_s[t][j][1]; }
        float mu = s1 * (1.0f / 128.0f);
        float var = s2 * (1.0f / 128.0f) - mu * mu;
        mu_s[t] = mu;
        rs_s[t] = rsqrtf(var + 1e-5f);
    }
    __syncthreads();

    float gl = lng[t], bl = lnb[t];
#pragma unroll
    for (int n = 0; n < 16; ++n)
        norm_s[n][t] = (sl_s[n][t] - mu_s[n]) * rs_s[n] * gl + bl;
    __syncthreads();

    const float4* wq = (const float4*)(Wq + (size_t)t * 128);
    float qn[16];
#pragma unroll
    for (int n = 0; n < 16; ++n) qn[n] = 0.f;
#pragma unroll 4
    for (int j = 0; j < 32; ++j) {
        float4 w4 = wq[j];
#pragma unroll
        for (int n = 0; n < 16; ++n) qn[n] += dot4(w4, *(const float4*)&norm_s[n][4 * j]);
    }
#pragma unroll
    for (int n = 0; n < 16; ++n) q_s[n][t] = qn[n];

    // zero acc (used by atomic fallback only; cheap) + den (both paths)
    float4 z4 = make_float4(0.f, 0.f, 0.f, 0.f);
    float4* ab = (float4*)(acc + (size_t)b * 2048);
#pragma unroll
    for (int i = 0; i < 4; ++i) ab[i * 128 + t] = z4;
    if (t < 16) den[b * 16 + t] = 0.f;
    __syncthreads();

    unsigned int* qo = q_out + (size_t)b * 1024;
#pragma unroll
    for (int i = 0; i < 8; ++i) {
        int u = i * 128 + t;
        int n = u >> 6, e2 = u & 63;
        qo[n * 64 + e2] = pk_bf16(q_s[n][2 * e2], q_s[n][2 * e2 + 1]);
    }
}

// ---------------- Kernel 2: fused attention, MFMA logits -------------------
// grid (16 chunks, 64 batches) x 256 threads; block tile = 256 rows = 4
// sub-tiles of 64. Core = r8 (spill-free VGPR 56, conflicts fixed).
// PART=1: epilogue writes the block's [16n x 128d] partial tile to a PRIVATE
// slot with plain coalesced stores — rounds 0-8 all shared a 2-4M fp32
// atomicAdd epilogue whose dword volume showed up 1:1 in WRITE_SIZE (18MB),
// i.e. memory-side sub-line RMW atomics: the suspected invisible ~100us
// serializer behind the 111us floor. PART=0: atomic fallback (small ws).
template<int PART>
__global__ __launch_bounds__(256) void k_attn(
    const float* __restrict__ kg_, const float* __restrict__ vg_,
    const unsigned int* __restrict__ q_u, float* __restrict__ acc_g,
    float* __restrict__ part, float* __restrict__ denom_g) {
    const int t = threadIdx.x;
    const int w = t >> 6, l = t & 63;
    const int b = blockIdx.y;
    const int lm = l & 15;   // A-row n (q frag) / B-col m (k frag)
    const int g  = l >> 4;   // 8-wide d-chunk within a 32-d K-step
    const int dcol = t & 127;
    const int nh = t >> 7;   // m-half owned in PV

    __shared__ unsigned int lds_u[5632];
    unsigned int* k_s = lds_u;                    // [64 rows][68 dw] bf16 pairs
    float*        p_s = (float*)(lds_u + 4352);   // [64 rows][20] fp32

    uint4 qA[4];
    {
        const uint4* qb = (const uint4*)q_u + ((b * 16 + lm) * 16);
#pragma unroll
        for (int kk = 0; kk < 4; ++kk) qA[kk] = qb[kk * 4 + g];
    }

    float acc[16];
#pragma unroll
    for (int i = 0; i < 16; ++i) acc[i] = 0.f;
    float dn[4] = {0.f, 0.f, 0.f, 0.f};

    const size_t mbase = (size_t)b * NF_ + blockIdx.x * 256;
    const float4* kg4 = (const float4*)kg_ + (mbase + w * 16) * 32;  // own rows
    const float*  vgp = vg_ + mbase * 128 + dcol;

    for (int sub = 0; sub < 4; ++sub) {
        const float* vt = vgp + (size_t)(sub * 64 + nh * 32) * 128;

        // ---- 1. k loads first (vmcnt FIFO: k-pack wait won't drain v)
        const float4* kp = kg4 + sub * 64 * 32;
        float4 ka[4], kb4[4];
#pragma unroll
        for (int i = 0; i < 4; ++i) ka[i] = kp[i * 64 + l];
#pragma unroll
        for (int i = 0; i < 4; ++i) kb4[i] = kp[(4 + i) * 64 + l];

        // ---- 2. v prefetch octs 0,1
        float vva[8], vvb[8];
#pragma unroll
        for (int i = 0; i < 8; ++i) vva[i] = vt[i * 128];
#pragma unroll
        for (int i = 0; i < 8; ++i) vvb[i] = vt[(8 + i) * 128];

        // ---- pack + ds_write k (waits k only; v stays in flight)
#pragma unroll
        for (int i = 0; i < 4; ++i) {
            int r = w * 16 + 2 * i + (l >> 5);
            *(uint2*)&k_s[r * 68 + 2 * (l & 31)] =
                make_uint2(pk_bf16(ka[i].x, ka[i].y), pk_bf16(ka[i].z, ka[i].w));
        }
#pragma unroll
        for (int i = 0; i < 4; ++i) {
            int r = w * 16 + 2 * (4 + i) + (l >> 5);
            *(uint2*)&k_s[r * 68 + 2 * (l & 31)] =
                make_uint2(pk_bf16(kb4[i].x, kb4[i].y), pk_bf16(kb4[i].z, kb4[i].w));
        }

        // ---- logits via MFMA: S^T tile [16n x 16m] for this wave's rows
        f32x4 sacc = {0.f, 0.f, 0.f, 0.f};
#pragma unroll
        for (int kk = 0; kk < 4; ++kk) {
            uint4 kf = *(const uint4*)&k_s[(w * 16 + lm) * 68 + kk * 16 + g * 4];
            sacc = __builtin_amdgcn_mfma_f32_16x16x32_bf16(
                as_bf16x8(qA[kk]), as_bf16x8(kf), sacc, 0, 0, 0);
        }
        // softmax over n (lane holds n=4g+r at m-col lm); |logits| small.
        const float scale = 0.08838834764831845f;  // D^-0.5
        float e0 = __expf(sacc[0] * scale);
        float e1 = __expf(sacc[1] * scale);
        float e2 = __expf(sacc[2] * scale);
        float e3 = __expf(sacc[3] * scale);
        float se = (e0 + e1) + (e2 + e3);
        se += __shfl_xor(se, 16);
        se += __shfl_xor(se, 32);
        float rse = __builtin_amdgcn_rcpf(se);
        float4 pv4 = make_float4(e0 * rse, e1 * rse, e2 * rse, e3 * rse);
        dn[0] += pv4.x; dn[1] += pv4.y; dn[2] += pv4.z; dn[3] += pv4.w;
        *(float4*)&p_s[(w * 16 + lm) * 20 + g * 4] = pv4;
        __syncthreads();   // p rows from all 4 waves visible

        // ---- 3. PV over own 32 m-rows, all 16 n; 2-oct rolling prefetch.
#define PV_CONSUME(VREG, BASE)                                              \
        {                                                                   \
            _Pragma("unroll")                                               \
            for (int i = 0; i < 8; ++i) {                                   \
                int m = nh * 32 + (BASE) + i;                               \
                float vvi = VREG[i];                                        \
                float4 pa = *(const float4*)&p_s[m * 20 + 0];               \
                float4 pb = *(const float4*)&p_s[m * 20 + 4];               \
                float4 pc = *(const float4*)&p_s[m * 20 + 8];               \
                float4 pd = *(const float4*)&p_s[m * 20 + 12];              \
                acc[0]  = fmaf(pa.x, vvi, acc[0]);                          \
                acc[1]  = fmaf(pa.y, vvi, acc[1]);                          \
                acc[2]  = fmaf(pa.z, vvi, acc[2]);                          \
                acc[3]  = fmaf(pa.w, vvi, acc[3]);                          \
                acc[4]  = fmaf(pb.x, vvi, acc[4]);                          \
                acc[5]  = fmaf(pb.y, vvi, acc[5]);                          \
                acc[6]  = fmaf(pb.z, vvi, acc[6]);                          \
                acc[7]  = fmaf(pb.w, vvi, acc[7]);                          \
                acc[8]  = fmaf(pc.x, vvi, acc[8]);                          \
                acc[9]  = fmaf(pc.y, vvi, acc[9]);                          \
                acc[10] = fmaf(pc.z, vvi, acc[10]);                         \
                acc[11] = fmaf(pc.w, vvi, acc[11]);                         \
                acc[12] = fmaf(pd.x, vvi, acc[12]);                         \
                acc[13] = fmaf(pd.y, vvi, acc[13]);                         \
                acc[14] = fmaf(pd.z, vvi, acc[14]);                         \
                acc[15] = fmaf(pd.w, vvi, acc[15]);                         \
            }                                                               \
        }
        PV_CONSUME(vva, 0)
#pragma unroll
        for (int i = 0; i < 8; ++i) vva[i] = vt[(16 + i) * 128];
        PV_CONSUME(vvb, 8)
#pragma unroll
        for (int i = 0; i < 8; ++i) vvb[i] = vt[(24 + i) * 128];
        PV_CONSUME(vva, 16)
        PV_CONSUME(vvb, 24)
#undef PV_CONSUME
        __syncthreads();   // protect k_s/p_s before restage
    }

    // ---- epilogue ----
    // denom: reduce dn over m (lanes&15) then one atomic per (wave, n).
    // (16K atomics/dispatch total — negligible vs the 2-4M acc atomics.)
#pragma unroll
    for (int m = 1; m <= 8; m <<= 1) {
#pragma unroll
        for (int r = 0; r < 4; ++r) dn[r] += __shfl_xor(dn[r], m);
    }
    if (lm == 0) {
#pragma unroll
        for (int r = 0; r < 4; ++r)
            atomicAdd(denom_g + b * 16 + g * 4 + r, dn[r]);
    }
    // cross-nh reduce via LDS; stride 17 (coprime 32) = conflict-free
    float* red = (float*)lds_u;   // [128 dcol][17]
    if (nh == 1) {
#pragma unroll
        for (int n = 0; n < 16; ++n) red[dcol * 17 + n] = acc[n];
    }
    __syncthreads();
    if (nh == 0) {
        if (PART) {
            // plain stores to this block's private slot: [b][chunk][n][d]
            float* base = part + ((size_t)(b * 16 + blockIdx.x) * 16) * 128 + dcol;
#pragma unroll
            for (int n = 0; n < 16; ++n)
                base[n * 128] = acc[n] + red[dcol * 17 + n];
        } else {
            float* base = acc_g + (size_t)b * 2048 + dcol;
#pragma unroll
            for (int n = 0; n < 16; ++n)
                atomicAdd(base + n * 128, acc[n] + red[dcol * 17 + n]);
        }
    }
}

// ---------------- Kernel 3: GRU + LN + MLP + residual, 4 bn per block ------
// (r6-original structure — r8's 1024-block variant regressed, reverted.
// PART=1: att = sum of 16 chunk partials (coalesced, L2-resident).)
template<int PART>
__global__ __launch_bounds__(256) void k_final(
    const float* __restrict__ acc_g, const float* __restrict__ part,
    const float* __restrict__ denom_g, const float* __restrict__ slots,
    const float* __restrict__ W_ih, const float* __restrict__ W_hh,
    const float* __restrict__ b_ih, const float* __restrict__ b_n,
    const float* __restrict__ ffg, const float* __restrict__ ffb,
    const float* __restrict__ W0, const float* __restrict__ b0,
    const float* __restrict__ W1, const float* __restrict__ b1,
    float* __restrict__ out) {
    const int bn0 = blockIdx.x * 4;
    const int t = threadIdx.x;  // 0..255
    __shared__ float att_s[4][128], slot_s[4][128];
    __shared__ float gates_s[4][4][128];  // [bn][rs,is,in,hn][d]
    __shared__ float gru_s[4][128], gn_s[4][128];
    __shared__ float h_s[4][256];

    // load att/slot
#pragma unroll
    for (int idx = t; idx < 512; idx += 256) {
        int bi = idx >> 7, d = idx & 127;
        int bn = bn0 + bi;
        float den = denom_g[bn] + 1e-8f;
        float s;
        if (PART) {
            // part[b][c][n][d]: idx = ((b*16+c)*16+n)*128+d, c-stride 2048
            const float* pp = part + ((size_t)(bn >> 4) * 256 + (bn & 15)) * 128 + d;
            s = 0.f;
#pragma unroll
            for (int c = 0; c < 16; ++c) s += pp[c * 2048];
        } else {
            s = acc_g[(size_t)bn * 128 + d];
        }
        att_s[bi][d] = s / den;
        slot_s[bi][d] = slots[(size_t)bn * 128 + d];
    }
    __syncthreads();

    // gates: rows 0..383 (t<128 handles two rows)
    for (int g = t; g < 384; g += 256) {
        const float4* wi = (const float4*)(W_ih + (size_t)g * 128);
        const float4* wh = (const float4*)(W_hh + (size_t)g * 128);
        float si[4] = {0.f, 0.f, 0.f, 0.f}, sh[4] = {0.f, 0.f, 0.f, 0.f};
#pragma unroll 4
        for (int j = 0; j < 32; ++j) {
            float4 wi4 = wi[j], wh4 = wh[j];
#pragma unroll
            for (int bi = 0; bi < 4; ++bi) {
                si[bi] += dot4(wi4, *(const float4*)&att_s[bi][4 * j]);
                sh[bi] += dot4(wh4, *(const float4*)&slot_s[bi][4 * j]);
            }
        }
        float bih = b_ih[g];
        int d = g & 127;
#pragma unroll
        for (int bi = 0; bi < 4; ++bi) {
            if (g < 128)       gates_s[bi][0][d] = si[bi] + sh[bi] + bih;
            else if (g < 256)  gates_s[bi][1][d] = si[bi] + sh[bi] + bih;
            else { gates_s[bi][2][d] = si[bi] + bih; gates_s[bi][3][d] = sh[bi]; }
        }
    }
    __syncthreads();

    // GRU + LN: wave w handles bn (bn0+w); lanes own d = l, l+64
    {
        int bi = t >> 6, l = t & 63;
        float gr[2], s1 = 0.f, s2 = 0.f;
#pragma unroll
        for (int h = 0; h < 2; ++h) {
            int d = l + 64 * h;
            float rr = 1.f / (1.f + __expf(-gates_s[bi][0][d]));
            float ii = 1.f / (1.f + __expf(-gates_s[bi][1][d]));
            float nv = tanhf(gates_s[bi][2][d] + rr * (gates_s[bi][3][d] + b_n[d]));
            float gru = nv + ii * (slot_s[bi][d] - nv);
            gr[h] = gru;
            gru_s[bi][d] = gru;
            s1 += gru; s2 += gru * gru;
        }
#pragma unroll
        for (int m = 1; m < 64; m <<= 1) { s1 += __shfl_xor(s1, m); s2 += __shfl_xor(s2, m); }
        float mu = s1 * (1.0f / 128.0f);
        float var = s2 * (1.0f / 128.0f) - mu * mu;
        float rstd = rsqrtf(var + 1e-5f);
#pragma unroll
        for (int h = 0; h < 2; ++h) {
            int d = l + 64 * h;
            gn_s[bi][d] = (gr[h] - mu) * rstd * ffg[d] + ffb[d];
        }
    }
    __syncthreads();

    // MLP0: thread t = h-row, reuse W0 row across 4 bn
    {
        const float4* w0 = (const float4*)(W0 + (size_t)t * 128);
        float s[4] = {0.f, 0.f, 0.f, 0.f};
#pragma unroll 4
        for (int j = 0; j < 32; ++j) {
            float4 w4 = w0[j];
#pragma unroll
            for (int bi = 0; bi < 4; ++bi) s[bi] += dot4(w4, *(const float4*)&gn_s[bi][4 * j]);
        }
        float b0v = b0[t];
#pragma unroll
        for (int bi = 0; bi < 4; ++bi) h_s[bi][t] = fmaxf(s[bi] + b0v, 0.f);
    }
    __syncthreads();

    // MLP1: t<128 -> row t for bn {0,1}; t>=128 -> row t-128 for bn {2,3}
    {
        int dr = t & 127, bp = (t >> 7) * 2;
        const float4* w1 = (const float4*)(W1 + (size_t)dr * 256);
        float s[2] = {0.f, 0.f};
#pragma unroll 4
        for (int j = 0; j < 64; ++j) {
            float4 w4 = w1[j];
#pragma unroll
            for (int u = 0; u < 2; ++u) s[u] += dot4(w4, *(const float4*)&h_s[bp + u][4 * j]);
        }
        float b1v = b1[dr];
#pragma unroll
        for (int u = 0; u < 2; ++u) {
            int bi = bp + u;
            out[(size_t)(bn0 + bi) * 128 + dr] = gru_s[bi][dr] + s[u] + b1v - slot_s[bi][dr];
        }
    }
}

extern "C" void kernel_launch(void* const* d_in, const int* in_sizes, int n_in,
                              void* d_out, int out_size, void* d_ws, size_t ws_size,
                              hipStream_t stream) {
    const float* slots = (const float*)d_in[1];
    const float* k     = (const float*)d_in[2];
    const float* v     = (const float*)d_in[3];
    const float* Wq    = (const float*)d_in[4];
    const float* lng   = (const float*)d_in[5];
    const float* lnb   = (const float*)d_in[6];
    const float* W_ih  = (const float*)d_in[7];
    const float* W_hh  = (const float*)d_in[8];
    const float* b_ih  = (const float*)d_in[9];
    const float* b_n   = (const float*)d_in[10];
    const float* ffg   = (const float*)d_in[11];
    const float* ffb   = (const float*)d_in[12];
    const float* W0    = (const float*)d_in[13];
    const float* b0    = (const float*)d_in[14];
    const float* W1    = (const float*)d_in[15];
    const float* b1    = (const float*)d_in[16];

    char* ws = (char*)d_ws;
    unsigned int* q_u = (unsigned int*)ws;
    float* acc  = (float*)(ws + 262144);
    float* den  = (float*)(ws + 786432);
    float* partp = (float*)(ws + 1048576);   // 8.39 MB partial tiles

    const bool use_part = (ws_size >= (size_t)1048576 + 64u * 16u * 16u * 128u * 4u);

    k_q<<<dim3(B_), dim3(128), 0, stream>>>(slots, Wq, lng, lnb, q_u, acc, den);
    if (use_part) {
        k_attn<1><<<dim3(16, B_), dim3(256), 0, stream>>>(k, v, q_u, acc, partp, den);
        k_final<1><<<dim3(256), dim3(256), 0, stream>>>(acc, partp, den, slots,
                                                        W_ih, W_hh, b_ih, b_n, ffg, ffb,
                                                        W0, b0, W1, b1, (float*)d_out);
    } else {
        k_attn<0><<<dim3(16, B_), dim3(256), 0, stream>>>(k, v, q_u, acc, partp, den);
        k_final<0><<<dim3(256), dim3(256), 0, stream>>>(acc, partp, den, slots,
                                                        W_ih, W_hh, b_ih, b_n, ffg, ffb,
                                                        W0, b0, W1, b1, (float*)d_out);
    }
}